// Round 2
// baseline (424.655 us; speedup 1.0000x reference)
//
#include <hip/hip_runtime.h>
#include <hip/hip_fp16.h>
#include <stdint.h>

#define PLANE_HALVES (512u * 512u * 32u)   // 8388608 halves = 16 MB per plane

// ---------------- transpose planes [C=32][512][512] f32 -> [512][512][32] f16 ----
// LDS-tiled: block = 256 threads handles [c=32][x=128] for one y-row.
// Phase 1: float4 coalesced reads (16 B/lane) -> LDS tile (pitch 132 floats).
// Phase 2: strided LDS gather across c (2-way bank alias = free), f16 convert,
//          32 B/thread contiguous channels-last store.
// grid: 3 planes * 512 y * 4 xb = 6144 blocks
__global__ __launch_bounds__(256) void tp_planes(
    const float* __restrict__ pxy,
    const float* __restrict__ pyz,
    const float* __restrict__ pxz,
    __half* __restrict__ ws)
{
    __shared__ float tile[32 * 132];       // pitch 132: 16B-aligned rows, conflict-free ph2
    unsigned bid = blockIdx.x;
    unsigned p   = bid >> 11;              // 0..2
    unsigned rem = bid & 2047u;
    unsigned y   = rem >> 2;               // 0..511
    unsigned xb  = rem & 3u;               // 4 x-tiles of 128
    const float* __restrict__ src = (p == 0) ? pxy : (p == 1) ? pyz : pxz;

    unsigned t  = threadIdx.x;
    unsigned c  = t >> 3;                  // 0..31
    unsigned xi = t & 7u;                  // 0..7
    const float* srow = src + (size_t)c * 262144u + y * 512u + xb * 128u;
#pragma unroll
    for (int i = 0; i < 4; ++i) {
        float4 v = *reinterpret_cast<const float4*>(srow + xi * 4u + i * 32u);
        *reinterpret_cast<float4*>(&tile[c * 132u + xi * 4u + i * 32u]) = v;
    }
    __syncthreads();

    unsigned xw = t >> 1;                  // 0..127
    unsigned h  = t & 1u;
    unsigned c0 = h * 16u;
    __half2 o[8];
#pragma unroll
    for (int i = 0; i < 8; ++i) {
        float a = tile[(c0 + 2u * i) * 132u + xw];
        float b = tile[(c0 + 2u * i + 1u) * 132u + xw];
        o[i] = __floats2half2_rn(a, b);
    }
    __half* dst = ws + (size_t)p * PLANE_HALVES
                + (size_t)(y * 512u + xb * 128u + xw) * 32u + c0;
    reinterpret_cast<uint4*>(dst)[0] = reinterpret_cast<const uint4*>(o)[0];
    reinterpret_cast<uint4*>(dst)[1] = reinterpret_cast<const uint4*>(o)[1];
}

// ---------------- transpose lines [C=32][512][1] f32 -> [512][32] f32 ------------
__global__ __launch_bounds__(256) void tp_lines(
    const float* __restrict__ lx, const float* __restrict__ ly,
    const float* __restrict__ lz, float* __restrict__ wl)
{
    int e = blockIdx.x * 256 + threadIdx.x;   // 3*512*32 = 49152
    int l = e >> 14;
    int r = e & 16383;
    int h = r >> 5;
    int c = r & 31;
    const float* src = (l == 0) ? lx : (l == 1) ? ly : lz;
    wl[e] = src[c * 512 + h];
}

// ---------------- fused sample + MLP ---------------------------------------------
struct LI { int i0, i1; float w0, w1; };

__device__ inline LI mk(float g) {
    float t = (g + 1.0f) * 0.5f * 511.0f;
    float f = floorf(t);
    LI r;
    r.w1 = t - f;
    r.w0 = 1.0f - r.w1;
    int i0 = (int)f;
    i0 = i0 < 0 ? 0 : (i0 > 511 ? 511 : i0);
    r.i0 = i0;
    r.i1 = i0 < 511 ? i0 + 1 : 511;   // if i1 clamped, w1==0 -> matches zero-pad
    return r;
}

__device__ inline void load8h(const __half* __restrict__ p, float o[8]) {
    uint4 u = *reinterpret_cast<const uint4*>(p);
    __half2 h0 = *reinterpret_cast<__half2*>(&u.x);
    __half2 h1 = *reinterpret_cast<__half2*>(&u.y);
    __half2 h2 = *reinterpret_cast<__half2*>(&u.z);
    __half2 h3 = *reinterpret_cast<__half2*>(&u.w);
    float2 f0 = __half22float2(h0), f1 = __half22float2(h1);
    float2 f2 = __half22float2(h2), f3 = __half22float2(h3);
    o[0] = f0.x; o[1] = f0.y; o[2] = f1.x; o[3] = f1.y;
    o[4] = f2.x; o[5] = f2.y; o[6] = f3.x; o[7] = f3.y;
}

// plane is channels-last [H][W][32] f16; H interp = Hi, W interp = Wi
__device__ inline void bilerp8(const __half* __restrict__ plane,
                               const LI& Hi, const LI& Wi, int c0, float o[8]) {
    float w00 = Hi.w0 * Wi.w0, w01 = Hi.w0 * Wi.w1;
    float w10 = Hi.w1 * Wi.w0, w11 = Hi.w1 * Wi.w1;
    const __half* b00 = plane + ((size_t)(Hi.i0 * 512 + Wi.i0) * 32 + c0);
    const __half* b01 = plane + ((size_t)(Hi.i0 * 512 + Wi.i1) * 32 + c0);
    const __half* b10 = plane + ((size_t)(Hi.i1 * 512 + Wi.i0) * 32 + c0);
    const __half* b11 = plane + ((size_t)(Hi.i1 * 512 + Wi.i1) * 32 + c0);
    float v00[8], v01[8], v10[8], v11[8];
    load8h(b00, v00); load8h(b01, v01); load8h(b10, v10); load8h(b11, v11);
#pragma unroll
    for (int i = 0; i < 8; ++i)
        o[i] = v00[i] * w00 + v01[i] * w01 + v10[i] * w10 + v11[i] * w11;
}

// line is [512][32] f32
__device__ inline void lerp8(const float* __restrict__ line,
                             const LI& L, int c0, float o[8]) {
    const float4* a = reinterpret_cast<const float4*>(line + L.i0 * 32 + c0);
    const float4* b = reinterpret_cast<const float4*>(line + L.i1 * 32 + c0);
    float4 a0 = a[0], a1 = a[1], b0 = b[0], b1 = b[1];
    o[0] = a0.x * L.w0 + b0.x * L.w1;
    o[1] = a0.y * L.w0 + b0.y * L.w1;
    o[2] = a0.z * L.w0 + b0.z * L.w1;
    o[3] = a0.w * L.w0 + b0.w * L.w1;
    o[4] = a1.x * L.w0 + b1.x * L.w1;
    o[5] = a1.y * L.w0 + b1.y * L.w1;
    o[6] = a1.z * L.w0 + b1.z * L.w1;
    o[7] = a1.w * L.w0 + b1.w * L.w1;
}

__global__ __launch_bounds__(256) void tensorf_fused(
    const float* __restrict__ coords,
    const __half* __restrict__ wsp,
    const float* __restrict__ wsl,
    const float* __restrict__ W1,
    const float* __restrict__ b1,
    const float* __restrict__ W2,
    const float* __restrict__ b2,
    float* __restrict__ out, int P)
{
    __shared__ float sW1[4096];   // [c=32][j=128]
    __shared__ float sB1[128];
    __shared__ float sW2[128];
    int tid = threadIdx.x;
#pragma unroll
    for (int i = 0; i < 4; ++i)
        reinterpret_cast<float4*>(sW1)[tid + 256 * i] =
            reinterpret_cast<const float4*>(W1)[tid + 256 * i];
    if (tid < 32)
        reinterpret_cast<float4*>(sB1)[tid] = reinterpret_cast<const float4*>(b1)[tid];
    if (tid >= 32 && tid < 64)
        reinterpret_cast<float4*>(sW2)[tid - 32] = reinterpret_cast<const float4*>(W2)[tid - 32];
    __syncthreads();

    int p = blockIdx.x * 256 + tid;
    if (p < P) {
        float x = coords[3 * p + 0];
        float y = coords[3 * p + 1];
        float z = coords[3 * p + 2];
        LI ax = mk(x), ay = mk(y), az = mk(z);
        const __half* pXY = wsp;                  // H from y, W from x
        const __half* pYZ = wsp + 8388608u;       // H from z, W from y
        const __half* pXZ = wsp + 16777216u;      // H from z, W from x
        const float* lX = wsl;
        const float* lY = wsl + 16384;
        const float* lZ = wsl + 32768;

        float feat[32];
#pragma unroll
        for (int ch = 0; ch < 4; ++ch) {
            int c0 = ch * 8;
            float pv[8], lv[8];
            // features = x_embed*yz + y_embed*xz + z_embed*xy
            bilerp8(pYZ, az, ay, c0, pv);
            lerp8(lX, ax, c0, lv);
#pragma unroll
            for (int i = 0; i < 8; ++i) feat[c0 + i] = lv[i] * pv[i];

            bilerp8(pXZ, az, ax, c0, pv);
            lerp8(lY, ay, c0, lv);
#pragma unroll
            for (int i = 0; i < 8; ++i) feat[c0 + i] = fmaf(lv[i], pv[i], feat[c0 + i]);

            bilerp8(pXY, ay, ax, c0, pv);
            lerp8(lZ, az, c0, lv);
#pragma unroll
            for (int i = 0; i < 8; ++i) feat[c0 + i] = fmaf(lv[i], pv[i], feat[c0 + i]);
        }

        // MLP: h = relu(f @ W1 + b1); out = h @ W2 + b2
        float acc = b2[0];
        for (int jc = 0; jc < 32; ++jc) {
            float4 h = reinterpret_cast<float4*>(sB1)[jc];
#pragma unroll
            for (int c = 0; c < 32; ++c) {
                float4 w = reinterpret_cast<float4*>(sW1)[c * 32 + jc];
                float f = feat[c];
                h.x = fmaf(f, w.x, h.x);
                h.y = fmaf(f, w.y, h.y);
                h.z = fmaf(f, w.z, h.z);
                h.w = fmaf(f, w.w, h.w);
            }
            h.x = fmaxf(h.x, 0.f); h.y = fmaxf(h.y, 0.f);
            h.z = fmaxf(h.z, 0.f); h.w = fmaxf(h.w, 0.f);
            float4 w2 = reinterpret_cast<float4*>(sW2)[jc];
            acc = fmaf(h.x, w2.x, acc);
            acc = fmaf(h.y, w2.y, acc);
            acc = fmaf(h.z, w2.z, acc);
            acc = fmaf(h.w, w2.w, acc);
        }
        out[p] = acc;
    }
}

extern "C" void kernel_launch(void* const* d_in, const int* in_sizes, int n_in,
                              void* d_out, int out_size, void* d_ws, size_t ws_size,
                              hipStream_t stream)
{
    const float* coords   = (const float*)d_in[0];
    const float* line_x   = (const float*)d_in[1];
    const float* line_y   = (const float*)d_in[2];
    const float* line_z   = (const float*)d_in[3];
    const float* plane_xy = (const float*)d_in[4];
    const float* plane_yz = (const float*)d_in[5];
    const float* plane_xz = (const float*)d_in[6];
    const float* W1 = (const float*)d_in[7];
    const float* b1 = (const float*)d_in[8];
    const float* W2 = (const float*)d_in[9];
    const float* b2 = (const float*)d_in[10];
    int P = in_sizes[0] / 3;

    size_t need = 3ull * PLANE_HALVES * 2ull + 3ull * 512ull * 32ull * 4ull;
    if (ws_size < need) return;   // loud failure rather than memory corruption

    __half* wsp = (__half*)d_ws;
    float*  wsl = (float*)((char*)d_ws + 3ull * PLANE_HALVES * 2ull);

    tp_planes<<<6144, 256, 0, stream>>>(plane_xy, plane_yz, plane_xz, wsp);
    tp_lines<<<192, 256, 0, stream>>>(line_x, line_y, line_z, wsl);

    int grid = (P + 255) / 256;
    tensorf_fused<<<grid, 256, 0, stream>>>(coords, wsp, wsl, W1, b1, W2, b2,
                                            (float*)d_out, P);
}

// Round 3
// 314.635 us; speedup vs baseline: 1.3497x; 1.3497x over previous
//
#include <hip/hip_runtime.h>
#include <hip/hip_fp16.h>
#include <stdint.h>

#define PLANE_HALVES (512u * 512u * 32u)   // 8388608 halves = 16 MB per plane

typedef _Float16 f16x8 __attribute__((ext_vector_type(8)));
typedef float    f32x4 __attribute__((ext_vector_type(4)));

// ---------------- transpose planes [C=32][512][512] f32 -> [512][512][32] f16 ----
__global__ __launch_bounds__(256) void tp_planes(
    const float* __restrict__ pxy,
    const float* __restrict__ pyz,
    const float* __restrict__ pxz,
    __half* __restrict__ ws)
{
    __shared__ float tile[32 * 132];
    unsigned bid = blockIdx.x;
    unsigned p   = bid >> 11;              // 0..2
    unsigned rem = bid & 2047u;
    unsigned y   = rem >> 2;               // 0..511
    unsigned xb  = rem & 3u;               // 4 x-tiles of 128
    const float* __restrict__ src = (p == 0) ? pxy : (p == 1) ? pyz : pxz;

    unsigned t  = threadIdx.x;
    unsigned c  = t >> 3;                  // 0..31
    unsigned xi = t & 7u;                  // 0..7
    const float* srow = src + (size_t)c * 262144u + y * 512u + xb * 128u;
#pragma unroll
    for (int i = 0; i < 4; ++i) {
        float4 v = *reinterpret_cast<const float4*>(srow + xi * 4u + i * 32u);
        *reinterpret_cast<float4*>(&tile[c * 132u + xi * 4u + i * 32u]) = v;
    }
    __syncthreads();

    unsigned xw = t >> 1;                  // 0..127
    unsigned h  = t & 1u;
    unsigned c0 = h * 16u;
    __half2 o[8];
#pragma unroll
    for (int i = 0; i < 8; ++i) {
        float a = tile[(c0 + 2u * i) * 132u + xw];
        float b = tile[(c0 + 2u * i + 1u) * 132u + xw];
        o[i] = __floats2half2_rn(a, b);
    }
    __half* dst = ws + (size_t)p * PLANE_HALVES
                + (size_t)(y * 512u + xb * 128u + xw) * 32u + c0;
    reinterpret_cast<uint4*>(dst)[0] = reinterpret_cast<const uint4*>(o)[0];
    reinterpret_cast<uint4*>(dst)[1] = reinterpret_cast<const uint4*>(o)[1];
}

// -------- transpose lines + repack W1 into f16 B-fragments -----------------------
// w1f layout: idx = (ch*64 + lane)*8 + e  -> W1[k][n], k = (lane>>4)*8+e,
// n = ch*16 + (lane&15). Same (q,e)->k placement as the A side (feat channels),
// so the MFMA contraction pairs channel c with W1 row c regardless of the ISA's
// exact k wiring (A/B k-layouts are symmetric).
__global__ __launch_bounds__(256) void tp_lines_w1(
    const float* __restrict__ lx, const float* __restrict__ ly,
    const float* __restrict__ lz, float* __restrict__ wl,
    const float* __restrict__ W1, __half* __restrict__ w1f)
{
    if (blockIdx.x < 192) {
        int e = blockIdx.x * 256 + threadIdx.x;   // 3*512*32 = 49152
        int l = e >> 14;
        int r = e & 16383;
        int h = r >> 5;
        int c = r & 31;
        const float* src = (l == 0) ? lx : (l == 1) ? ly : lz;
        wl[e] = src[c * 512 + h];
    } else {
        int t = threadIdx.x;
#pragma unroll
        for (int i = 0; i < 16; ++i) {
            int idx = t * 16 + i;              // 0..4095
            int e  = idx & 7;
            int ln = (idx >> 3) & 63;
            int ch = idx >> 9;
            int k = ((ln >> 4) << 3) + e;
            int n = (ch << 4) + (ln & 15);
            w1f[idx] = __float2half(W1[k * 128 + n]);
        }
    }
}

// ---------------- fused sample + MFMA MLP ----------------------------------------
struct LI { int i0, i1; float w0, w1; };

__device__ inline LI mk(float g) {
    float t = (g + 1.0f) * 0.5f * 511.0f;
    float f = floorf(t);
    LI r;
    r.w1 = t - f;
    r.w0 = 1.0f - r.w1;
    int i0 = (int)f;
    i0 = i0 < 0 ? 0 : (i0 > 511 ? 511 : i0);
    r.i0 = i0;
    r.i1 = i0 < 511 ? i0 + 1 : 511;   // if i1 clamped, w1==0 -> matches zero-pad
    return r;
}

__device__ inline void load8h(const __half* __restrict__ p, float o[8]) {
    uint4 u = *reinterpret_cast<const uint4*>(p);
    __half2 h0 = *reinterpret_cast<__half2*>(&u.x);
    __half2 h1 = *reinterpret_cast<__half2*>(&u.y);
    __half2 h2 = *reinterpret_cast<__half2*>(&u.z);
    __half2 h3 = *reinterpret_cast<__half2*>(&u.w);
    float2 f0 = __half22float2(h0), f1 = __half22float2(h1);
    float2 f2 = __half22float2(h2), f3 = __half22float2(h3);
    o[0] = f0.x; o[1] = f0.y; o[2] = f1.x; o[3] = f1.y;
    o[4] = f2.x; o[5] = f2.y; o[6] = f3.x; o[7] = f3.y;
}

// plane is channels-last [H][W][32] f16; 4 lanes (q=0..3) of a point read 64B contiguous
__device__ inline void bilerp8(const __half* __restrict__ plane,
                               const LI& Hi, const LI& Wi, int c0, float o[8]) {
    float w00 = Hi.w0 * Wi.w0, w01 = Hi.w0 * Wi.w1;
    float w10 = Hi.w1 * Wi.w0, w11 = Hi.w1 * Wi.w1;
    const __half* b00 = plane + ((size_t)(Hi.i0 * 512 + Wi.i0) * 32 + c0);
    const __half* b01 = plane + ((size_t)(Hi.i0 * 512 + Wi.i1) * 32 + c0);
    const __half* b10 = plane + ((size_t)(Hi.i1 * 512 + Wi.i0) * 32 + c0);
    const __half* b11 = plane + ((size_t)(Hi.i1 * 512 + Wi.i1) * 32 + c0);
    float v00[8], v01[8], v10[8], v11[8];
    load8h(b00, v00); load8h(b01, v01); load8h(b10, v10); load8h(b11, v11);
#pragma unroll
    for (int i = 0; i < 8; ++i)
        o[i] = v00[i] * w00 + v01[i] * w01 + v10[i] * w10 + v11[i] * w11;
}

// line is [512][32] f32
__device__ inline void lerp8(const float* __restrict__ line,
                             const LI& L, int c0, float o[8]) {
    const float4* a = reinterpret_cast<const float4*>(line + L.i0 * 32 + c0);
    const float4* b = reinterpret_cast<const float4*>(line + L.i1 * 32 + c0);
    float4 a0 = a[0], a1 = a[1], b0 = b[0], b1 = b[1];
    o[0] = a0.x * L.w0 + b0.x * L.w1;
    o[1] = a0.y * L.w0 + b0.y * L.w1;
    o[2] = a0.z * L.w0 + b0.z * L.w1;
    o[3] = a0.w * L.w0 + b0.w * L.w1;
    o[4] = a1.x * L.w0 + b1.x * L.w1;
    o[5] = a1.y * L.w0 + b1.y * L.w1;
    o[6] = a1.z * L.w0 + b1.z * L.w1;
    o[7] = a1.w * L.w0 + b1.w * L.w1;
}

// Wave = 64 points (4 m-tiles of 16). lane = q*16 + r: r = point-in-tile,
// q = channel-group (8 ch). Lane's blended 8 channels (f16) == MFMA A-fragment.
// MLP: 8 j-chunks x 4 mfma_f32_16x16x32_f16; C seeded with b1; relu+W2 in epilogue;
// shfl_xor reduce over 16 j-columns. C layout (m89): col=lane&15, row=(lane>>4)*4+reg.
__global__ __launch_bounds__(256) void tensorf_fused(
    const float* __restrict__ coords,
    const __half* __restrict__ wsp,
    const float* __restrict__ wsl,
    const __half* __restrict__ w1f,
    const float* __restrict__ b1,
    const float* __restrict__ W2,
    const float* __restrict__ b2,
    float* __restrict__ out, int P)
{
    __shared__ __align__(16) _Float16 sW1f[4096];   // 8 KB, B-fragment order
    __shared__ float sB1[128];
    __shared__ float sW2[128];
    int tid = threadIdx.x;
    reinterpret_cast<uint4*>(sW1f)[tid]       = reinterpret_cast<const uint4*>(w1f)[tid];
    reinterpret_cast<uint4*>(sW1f)[tid + 256] = reinterpret_cast<const uint4*>(w1f)[tid + 256];
    if (tid < 32)
        reinterpret_cast<float4*>(sB1)[tid] = reinterpret_cast<const float4*>(b1)[tid];
    else if (tid < 64)
        reinterpret_cast<float4*>(sW2)[tid - 32] = reinterpret_cast<const float4*>(W2)[tid - 32];
    __syncthreads();

    int lane = tid & 63;
    int wv   = tid >> 6;
    int r    = lane & 15;
    int q    = lane >> 4;
    int c0   = q * 8;
    int base = blockIdx.x * 256 + wv * 64;

    const __half* pXY = wsp;                  // H from y, W from x
    const __half* pYZ = wsp + 8388608u;       // H from z, W from y
    const __half* pXZ = wsp + 16777216u;      // H from z, W from x
    const float* lX = wsl;
    const float* lY = wsl + 16384;
    const float* lZ = wsl + 32768;

    f16x8 af[4];
#pragma unroll
    for (int m = 0; m < 4; ++m) {
        int p  = base + m * 16 + r;
        int pc = p < P ? p : P - 1;
        float x = coords[3 * pc + 0];
        float y = coords[3 * pc + 1];
        float z = coords[3 * pc + 2];
        LI ax = mk(x), ay = mk(y), az = mk(z);

        float f[8], pv[8], lv[8];
        // features = x_embed*yz + y_embed*xz + z_embed*xy
        bilerp8(pYZ, az, ay, c0, pv);
        lerp8(lX, ax, c0, lv);
#pragma unroll
        for (int i = 0; i < 8; ++i) f[i] = lv[i] * pv[i];

        bilerp8(pXZ, az, ax, c0, pv);
        lerp8(lY, ay, c0, lv);
#pragma unroll
        for (int i = 0; i < 8; ++i) f[i] = fmaf(lv[i], pv[i], f[i]);

        bilerp8(pXY, ay, ax, c0, pv);
        lerp8(lZ, az, c0, lv);
#pragma unroll
        for (int i = 0; i < 8; ++i) f[i] = fmaf(lv[i], pv[i], f[i]);

        f16x8 a;
#pragma unroll
        for (int i = 0; i < 8; ++i) a[i] = (_Float16)f[i];
        af[m] = a;
    }

    float accm[4][4];
#pragma unroll
    for (int m = 0; m < 4; ++m)
#pragma unroll
        for (int t = 0; t < 4; ++t) accm[m][t] = 0.f;

#pragma unroll
    for (int ch = 0; ch < 8; ++ch) {
        f16x8 bf = *reinterpret_cast<const f16x8*>(&sW1f[(ch * 64 + lane) * 8]);
        float bb  = sB1[ch * 16 + r];
        float w2v = sW2[ch * 16 + r];
#pragma unroll
        for (int m = 0; m < 4; ++m) {
            f32x4 cacc = {bb, bb, bb, bb};
            cacc = __builtin_amdgcn_mfma_f32_16x16x32_f16(af[m], bf, cacc, 0, 0, 0);
#pragma unroll
            for (int t = 0; t < 4; ++t) {
                float h = fmaxf(cacc[t], 0.f);
                accm[m][t] = fmaf(h, w2v, accm[m][t]);
            }
        }
    }

    // reduce over the 16 j-columns (lane&15 groups)
#pragma unroll
    for (int m = 0; m < 4; ++m)
#pragma unroll
        for (int t = 0; t < 4; ++t) {
            float v = accm[m][t];
            v += __shfl_xor(v, 1);
            v += __shfl_xor(v, 2);
            v += __shfl_xor(v, 4);
            v += __shfl_xor(v, 8);
            accm[m][t] = v;
        }

    if (r == 0) {
        float b2v = b2[0];
#pragma unroll
        for (int m = 0; m < 4; ++m)
#pragma unroll
            for (int t = 0; t < 4; ++t) {
                int p = base + m * 16 + q * 4 + t;   // C row = q*4 + reg
                if (p < P) out[p] = accm[m][t] + b2v;
            }
    }
}

extern "C" void kernel_launch(void* const* d_in, const int* in_sizes, int n_in,
                              void* d_out, int out_size, void* d_ws, size_t ws_size,
                              hipStream_t stream)
{
    const float* coords   = (const float*)d_in[0];
    const float* line_x   = (const float*)d_in[1];
    const float* line_y   = (const float*)d_in[2];
    const float* line_z   = (const float*)d_in[3];
    const float* plane_xy = (const float*)d_in[4];
    const float* plane_yz = (const float*)d_in[5];
    const float* plane_xz = (const float*)d_in[6];
    const float* W1 = (const float*)d_in[7];
    const float* b1 = (const float*)d_in[8];
    const float* W2 = (const float*)d_in[9];
    const float* b2 = (const float*)d_in[10];
    int P = in_sizes[0] / 3;

    size_t planes_b = 3ull * PLANE_HALVES * 2ull;
    size_t lines_b  = 3ull * 512ull * 32ull * 4ull;
    size_t w1f_b    = 4096ull * 2ull;
    if (ws_size < planes_b + lines_b + w1f_b) return;

    __half* wsp = (__half*)d_ws;
    float*  wsl = (float*)((char*)d_ws + planes_b);
    __half* w1f = (__half*)((char*)d_ws + planes_b + lines_b);

    tp_planes<<<6144, 256, 0, stream>>>(plane_xy, plane_yz, plane_xz, wsp);
    tp_lines_w1<<<193, 256, 0, stream>>>(line_x, line_y, line_z, wsl, W1, w1f);

    int grid = (P + 255) / 256;
    tensorf_fused<<<grid, 256, 0, stream>>>(coords, wsp, wsl, w1f, b1, W2, b2,
                                            (float*)d_out, P);
}